// Round 5
// baseline (473.211 us; speedup 1.0000x reference)
//
#include <hip/hip_runtime.h>
#include <hip/hip_bf16.h>

// out[i] = 10 * min_j ||x_i - y_j||, x: 8192x96 f32, y: 65536x96 f32.
// sq = x2[i] + (y2[j] - 2*x.y): bf16 MFMA computes (y2 - 2*x.y) by pre-scaling
// train by -2 (exact in bf16) and preloading y2 as the MFMA C operand.
// R5: no-LDS main kernel (R4) + TSPLIT=64 -> 2048 WGs = 8 WG/CU (full
// occupancy; R4 was grid-capped at 4 WG/CU / 41%), launch_bounds(256,8) to
// keep VGPR<=64, peeled last iteration + pointer strength-reduction, and an
// LDS-atomic-free prep (quad shuffle-reduce row norms).

typedef __attribute__((ext_vector_type(8))) short bf16x8;
typedef __attribute__((ext_vector_type(4))) float f32x4;

#define NQ 8192
#define NT 65536
#define KD 96
#define QB 256            // queries per WG: 4 waves x 64
#define TSPLIT 64         // train chunks; chunk t -> XCD t%8, 1.6 MB/XCD in L2
#define TCHUNK (NT / TSPLIT)   // 1024 rows per WG
#define NTT (TCHUNK / 16)      // 64 MFMA row-tiles per WG

static __device__ __forceinline__ ushort f2bf(float f) {
  unsigned u = __float_as_uint(f);
  return (ushort)((u + 0x7fffu + ((u >> 16) & 1u)) >> 16);
}
static __device__ __forceinline__ unsigned pk2(float a, float b) {
  return (unsigned)f2bf(a) | ((unsigned)f2bf(b) << 16);
}

// Thread t owns float4s [6t, 6t+6) = one quarter-row (96B contiguous).
// Row norm = quad shuffle-reduce (xor 1, xor 2). No LDS, no barriers.
__global__ __launch_bounds__(256) void prep_kernel(
    const float* __restrict__ qf, const float* __restrict__ tf,
    ushort* __restrict__ qbf, ushort* __restrict__ tbf,
    float* __restrict__ x2, float* __restrict__ y2,
    float* __restrict__ outp)
{
  const int tid = threadIdx.x;
  const int b = blockIdx.x;
  const bool isq = b < (NQ / 64);
  const int rb = isq ? b : b - (NQ / 64);
  const float4* src = (const float4*)((isq ? qf : tf) + (size_t)rb * 64 * KD);
  uint2* dst = (uint2*)((isq ? qbf : tbf) + (size_t)rb * 64 * KD);
  const float scale = isq ? 1.0f : -2.0f;

  float s = 0.0f;
  #pragma unroll
  for (int i = 0; i < 6; ++i) {
    float4 v = src[tid * 6 + i];
    s += v.x * v.x + v.y * v.y + v.z * v.z + v.w * v.w;
    uint2 p; p.x = pk2(v.x * scale, v.y * scale); p.y = pk2(v.z * scale, v.w * scale);
    dst[tid * 6 + i] = p;
  }
  s += __shfl_xor(s, 1, 64);
  s += __shfl_xor(s, 2, 64);
  if ((tid & 3) == 0) {
    int row = rb * 64 + (tid >> 2);
    if (isq) { x2[row] = s; outp[row] = __uint_as_float(0x7f800000u); }
    else     { y2[row] = s; }
  }
}

__global__ __launch_bounds__(256, 8) void min_dist_kernel(
    const ushort* __restrict__ qbf, const ushort* __restrict__ tbf,
    const float* __restrict__ x2, const float* __restrict__ y2,
    float* __restrict__ outp)
{
  const int tid  = threadIdx.x;
  const int w    = tid >> 6;
  const int lane = tid & 63;
  const int quad = lane >> 4;
  const int n    = lane & 15;
  const int tsplit = blockIdx.x & (TSPLIT - 1);   // -> XCD tsplit%8
  const int qblock = blockIdx.x / TSPLIT;
  const int qbase  = qblock * QB + w * 64;

  // B-operand (query) fragments: 4 col-tiles x 3 k-blocks = 48 VGPRs, resident
  bf16x8 bq[4][3];
  #pragma unroll
  for (int ct = 0; ct < 4; ++ct) {
    const ushort* qp = qbf + (size_t)(qbase + ct * 16 + n) * KD + quad * 8;
    #pragma unroll
    for (int kb = 0; kb < 3; ++kb)
      bq[ct][kb] = *(const bf16x8*)(qp + kb * 32);
  }

  const float INF = __uint_as_float(0x7f800000u);
  float m0 = INF, m1 = INF, m2 = INF, m3 = INF;

  const int trow0 = tsplit * TCHUNK;
  // lane-fixed fragment base; 16 rows = 16*KD ushorts per tt
  const ushort* tp = tbf + (size_t)(trow0 + n) * KD + quad * 8;
  const float*  yp = y2 + trow0 + quad * 4;

  // load tt=0
  bf16x8 a0 = *(const bf16x8*)(tp);
  bf16x8 a1 = *(const bf16x8*)(tp + 32);
  bf16x8 a2 = *(const bf16x8*)(tp + 64);
  f32x4  yv = *(const f32x4*)(yp);

  const ushort* tpn = tp + 16 * KD;
  const float*  ypn = yp + 16;

  #pragma unroll 1
  for (int t = 0; t < NTT - 1; ++t) {
    bf16x8 na0 = *(const bf16x8*)(tpn);
    bf16x8 na1 = *(const bf16x8*)(tpn + 32);
    bf16x8 na2 = *(const bf16x8*)(tpn + 64);
    f32x4  nyv = *(const f32x4*)(ypn);
    tpn += 16 * KD; ypn += 16;

    f32x4 acc;
    acc = __builtin_amdgcn_mfma_f32_16x16x32_bf16(a0, bq[0][0], yv, 0, 0, 0);
    acc = __builtin_amdgcn_mfma_f32_16x16x32_bf16(a1, bq[0][1], acc, 0, 0, 0);
    acc = __builtin_amdgcn_mfma_f32_16x16x32_bf16(a2, bq[0][2], acc, 0, 0, 0);
    m0 = fminf(fminf(fminf(acc[0], acc[1]), acc[2]), fminf(acc[3], m0));

    acc = __builtin_amdgcn_mfma_f32_16x16x32_bf16(a0, bq[1][0], yv, 0, 0, 0);
    acc = __builtin_amdgcn_mfma_f32_16x16x32_bf16(a1, bq[1][1], acc, 0, 0, 0);
    acc = __builtin_amdgcn_mfma_f32_16x16x32_bf16(a2, bq[1][2], acc, 0, 0, 0);
    m1 = fminf(fminf(fminf(acc[0], acc[1]), acc[2]), fminf(acc[3], m1));

    acc = __builtin_amdgcn_mfma_f32_16x16x32_bf16(a0, bq[2][0], yv, 0, 0, 0);
    acc = __builtin_amdgcn_mfma_f32_16x16x32_bf16(a1, bq[2][1], acc, 0, 0, 0);
    acc = __builtin_amdgcn_mfma_f32_16x16x32_bf16(a2, bq[2][2], acc, 0, 0, 0);
    m2 = fminf(fminf(fminf(acc[0], acc[1]), acc[2]), fminf(acc[3], m2));

    acc = __builtin_amdgcn_mfma_f32_16x16x32_bf16(a0, bq[3][0], yv, 0, 0, 0);
    acc = __builtin_amdgcn_mfma_f32_16x16x32_bf16(a1, bq[3][1], acc, 0, 0, 0);
    acc = __builtin_amdgcn_mfma_f32_16x16x32_bf16(a2, bq[3][2], acc, 0, 0, 0);
    m3 = fminf(fminf(fminf(acc[0], acc[1]), acc[2]), fminf(acc[3], m3));

    a0 = na0; a1 = na1; a2 = na2; yv = nyv;
  }
  // final tile (no prefetch)
  {
    f32x4 acc;
    acc = __builtin_amdgcn_mfma_f32_16x16x32_bf16(a0, bq[0][0], yv, 0, 0, 0);
    acc = __builtin_amdgcn_mfma_f32_16x16x32_bf16(a1, bq[0][1], acc, 0, 0, 0);
    acc = __builtin_amdgcn_mfma_f32_16x16x32_bf16(a2, bq[0][2], acc, 0, 0, 0);
    m0 = fminf(fminf(fminf(acc[0], acc[1]), acc[2]), fminf(acc[3], m0));

    acc = __builtin_amdgcn_mfma_f32_16x16x32_bf16(a0, bq[1][0], yv, 0, 0, 0);
    acc = __builtin_amdgcn_mfma_f32_16x16x32_bf16(a1, bq[1][1], acc, 0, 0, 0);
    acc = __builtin_amdgcn_mfma_f32_16x16x32_bf16(a2, bq[1][2], acc, 0, 0, 0);
    m1 = fminf(fminf(fminf(acc[0], acc[1]), acc[2]), fminf(acc[3], m1));

    acc = __builtin_amdgcn_mfma_f32_16x16x32_bf16(a0, bq[2][0], yv, 0, 0, 0);
    acc = __builtin_amdgcn_mfma_f32_16x16x32_bf16(a1, bq[2][1], acc, 0, 0, 0);
    acc = __builtin_amdgcn_mfma_f32_16x16x32_bf16(a2, bq[2][2], acc, 0, 0, 0);
    m2 = fminf(fminf(fminf(acc[0], acc[1]), acc[2]), fminf(acc[3], m2));

    acc = __builtin_amdgcn_mfma_f32_16x16x32_bf16(a0, bq[3][0], yv, 0, 0, 0);
    acc = __builtin_amdgcn_mfma_f32_16x16x32_bf16(a1, bq[3][1], acc, 0, 0, 0);
    acc = __builtin_amdgcn_mfma_f32_16x16x32_bf16(a2, bq[3][2], acc, 0, 0, 0);
    m3 = fminf(fminf(fminf(acc[0], acc[1]), acc[2]), fminf(acc[3], m3));
  }

  // fold across quads (lanes with equal n hold the same query columns)
  float m[4] = {m0, m1, m2, m3};
  #pragma unroll
  for (int ct = 0; ct < 4; ++ct) {
    m[ct] = fminf(m[ct], __shfl_xor(m[ct], 16, 64));
    m[ct] = fminf(m[ct], __shfl_xor(m[ct], 32, 64));
  }
  if (quad == 0) {
    #pragma unroll
    for (int ct = 0; ct < 4; ++ct) {
      int q = qbase + ct * 16 + n;
      float sq = fmaxf(x2[q] + m[ct], 0.0f);
      float val = sqrtf(sq) * 10.0f;
      atomicMin((unsigned int*)&outp[q], __float_as_uint(val));
    }
  }
}

extern "C" void kernel_launch(void* const* d_in, const int* in_sizes, int n_in,
                              void* d_out, int out_size, void* d_ws, size_t ws_size,
                              hipStream_t stream) {
  const float* qf = (const float*)d_in[0];   // mutation_dist 8192x96
  const float* tf = (const float*)d_in[1];   // train_data   65536x96
  float* outp = (float*)d_out;               // 8192 f32

  ushort* qbf = (ushort*)d_ws;                // 8192*96 bf16
  ushort* tbf = qbf + (size_t)NQ * KD;        // 65536*96 bf16, pre-scaled -2
  float* x2 = (float*)(tbf + (size_t)NT * KD);
  float* y2 = x2 + NQ;

  prep_kernel<<<(NQ + NT) / 64, 256, 0, stream>>>(qf, tf, qbf, tbf, x2, y2, outp);
  min_dist_kernel<<<(NQ / QB) * TSPLIT, 256, 0, stream>>>(qbf, tbf, x2, y2, outp);
}

// Round 6
// 149.887 us; speedup vs baseline: 3.1571x; 3.1571x over previous
//
#include <hip/hip_runtime.h>
#include <hip/hip_bf16.h>

// out[i] = 10 * min_j ||x_i - y_j||, x: 8192x96 f32, y: 65536x96 f32.
// sq = x2[i] + (y2[j] - 2*x.y): bf16 MFMA computes (y2 - 2*x.y) by pre-scaling
// train by -2 (exact in bf16) and preloading y2 as the MFMA C operand.
// R6: R1's LDS-broadcast skeleton (best measured: 84us @53% Mfma) +
//  - fragment-major LDS layout (R2/R3-proven: SQ_LDS_BANK_CONFLICT -> 0)
//  - TSPLIT=64 -> 2048 WGs = 8 WG/CU grid; LDS 12.5 KB -> no LDS occupancy cap
//  - VOLATILE bq loads: R4/R5 showed the compiler sinks the 48-VGPR B-frag
//    loads into the K-loop (VGPR_Count 44/32 < 48), turning the kernel
//    TCP-bound. volatile forces one load, registers stay resident.
//  - simple 2-barrier tile loop (m97/m131-141: dbuf on this shape regresses)

typedef __attribute__((ext_vector_type(8))) short bf16x8;
typedef __attribute__((ext_vector_type(4))) float f32x4;

#define NQ 8192
#define NT 65536
#define KD 96
#define QB 256            // queries per WG: 4 waves x 64
#define TSPLIT 64         // train chunks; chunk t -> XCD t%8 (1.6MB+qbf in L2)
#define TCHUNK (NT / TSPLIT)   // 1024 rows per WG
#define TTILE 64          // train rows per LDS tile
#define TILES (TCHUNK / TTILE) // 16
#define FRAG_USH 512      // ushorts per (tt,kb) fragment block (64 lanes x 8)

static __device__ __forceinline__ ushort f2bf(float f) {
  unsigned u = __float_as_uint(f);
  return (ushort)((u + 0x7fffu + ((u >> 16) & 1u)) >> 16);
}
static __device__ __forceinline__ unsigned pk2(float a, float b) {
  return (unsigned)f2bf(a) | ((unsigned)f2bf(b) << 16);
}

// Thread t owns float4s [6t, 6t+6) = one quarter-row (96B contiguous).
// Row norm = quad shuffle-reduce (xor 1, xor 2). No LDS, no barriers.
__global__ __launch_bounds__(256) void prep_kernel(
    const float* __restrict__ qf, const float* __restrict__ tf,
    ushort* __restrict__ qbf, ushort* __restrict__ tbf,
    float* __restrict__ x2, float* __restrict__ y2,
    float* __restrict__ outp)
{
  const int tid = threadIdx.x;
  const int b = blockIdx.x;
  const bool isq = b < (NQ / 64);
  const int rb = isq ? b : b - (NQ / 64);
  const float4* src = (const float4*)((isq ? qf : tf) + (size_t)rb * 64 * KD);
  uint2* dst = (uint2*)((isq ? qbf : tbf) + (size_t)rb * 64 * KD);
  const float scale = isq ? 1.0f : -2.0f;

  float s = 0.0f;
  #pragma unroll
  for (int i = 0; i < 6; ++i) {
    float4 v = src[tid * 6 + i];
    s += v.x * v.x + v.y * v.y + v.z * v.z + v.w * v.w;
    uint2 p; p.x = pk2(v.x * scale, v.y * scale); p.y = pk2(v.z * scale, v.w * scale);
    dst[tid * 6 + i] = p;
  }
  s += __shfl_xor(s, 1, 64);
  s += __shfl_xor(s, 2, 64);
  if ((tid & 3) == 0) {
    int row = rb * 64 + (tid >> 2);
    if (isq) { x2[row] = s; outp[row] = __uint_as_float(0x7f800000u); }
    else     { y2[row] = s; }
  }
}

__global__ __launch_bounds__(256, 5) void min_dist_kernel(
    const ushort* __restrict__ qbf, const ushort* __restrict__ tbf,
    const float* __restrict__ x2, const float* __restrict__ y2,
    float* __restrict__ outp)
{
  // fragment-major A tile: [tt][kb] blocks of 64 lanes x 16B (conflict-free)
  __shared__ __align__(16) ushort ldsA[TTILE * KD];   // 12 KB
  __shared__ __align__(16) float ldsY[TTILE];

  const int tid  = threadIdx.x;
  const int w    = tid >> 6;
  const int lane = tid & 63;
  const int quad = lane >> 4;
  const int n    = lane & 15;
  const int tsplit = blockIdx.x & (TSPLIT - 1);   // -> XCD tsplit%8
  const int qblock = blockIdx.x / TSPLIT;
  const int qbase  = qblock * QB + w * 64;

  // B-operand (query) fragments: 4 col-tiles x 3 k-blocks = 48 VGPRs.
  // volatile: forbid the compiler from sinking these loads into the K-loop
  // (R4/R5: it did, VGPR_Count dropped below 48 and the kernel went TCP-bound)
  bf16x8 bq[4][3];
  #pragma unroll
  for (int ct = 0; ct < 4; ++ct) {
    const ushort* qp = qbf + (size_t)(qbase + ct * 16 + n) * KD + quad * 8;
    #pragma unroll
    for (int kb = 0; kb < 3; ++kb)
      bq[ct][kb] = *(const volatile bf16x8*)(qp + kb * 32);
  }

  // staging map: thread stages 3 x 16B chunks, LDS lane-contiguous
  int goff[3], loff[3];
  #pragma unroll
  for (int it = 0; it < 3; ++it) {
    int o = it * 256 + tid;           // 16B chunk id 0..767
    int frag = o >> 6;                // tt*3+kb (wave-uniform)
    int tt = frag / 3, kb = frag - tt * 3;
    int l = o & 63;
    goff[it] = (tt * 16 + (l & 15)) * KD + kb * 32 + (l >> 4) * 8;  // ushort
    loff[it] = o * 8;                                                // ushort
  }

  const float INF = __uint_as_float(0x7f800000u);
  float m0 = INF, m1 = INF, m2 = INF, m3 = INF;

  const int trow0 = tsplit * TCHUNK;

  #pragma unroll 1
  for (int tile = 0; tile < TILES; ++tile) {
    const int tb = trow0 + tile * TTILE;
    const ushort* g = tbf + (size_t)tb * KD;
    __syncthreads();
    #pragma unroll
    for (int it = 0; it < 3; ++it)
      *(uint4*)&ldsA[loff[it]] = *(const uint4*)(g + goff[it]);
    if (tid < 16)
      *(f32x4*)&ldsY[tid * 4] = *(const f32x4*)(y2 + tb + tid * 4);
    __syncthreads();

    #pragma unroll
    for (int tt = 0; tt < 4; ++tt) {
      const ushort* ap = &ldsA[tt * 3 * FRAG_USH + lane * 8];
      bf16x8 a0 = *(const bf16x8*)(ap);
      bf16x8 a1 = *(const bf16x8*)(ap + FRAG_USH);
      bf16x8 a2 = *(const bf16x8*)(ap + 2 * FRAG_USH);
      f32x4 y2v = *(const f32x4*)&ldsY[tt * 16 + quad * 4];

      f32x4 acc;
      acc = __builtin_amdgcn_mfma_f32_16x16x32_bf16(a0, bq[0][0], y2v, 0, 0, 0);
      acc = __builtin_amdgcn_mfma_f32_16x16x32_bf16(a1, bq[0][1], acc, 0, 0, 0);
      acc = __builtin_amdgcn_mfma_f32_16x16x32_bf16(a2, bq[0][2], acc, 0, 0, 0);
      m0 = fminf(fminf(fminf(acc[0], acc[1]), acc[2]), fminf(acc[3], m0));

      acc = __builtin_amdgcn_mfma_f32_16x16x32_bf16(a0, bq[1][0], y2v, 0, 0, 0);
      acc = __builtin_amdgcn_mfma_f32_16x16x32_bf16(a1, bq[1][1], acc, 0, 0, 0);
      acc = __builtin_amdgcn_mfma_f32_16x16x32_bf16(a2, bq[1][2], acc, 0, 0, 0);
      m1 = fminf(fminf(fminf(acc[0], acc[1]), acc[2]), fminf(acc[3], m1));

      acc = __builtin_amdgcn_mfma_f32_16x16x32_bf16(a0, bq[2][0], y2v, 0, 0, 0);
      acc = __builtin_amdgcn_mfma_f32_16x16x32_bf16(a1, bq[2][1], acc, 0, 0, 0);
      acc = __builtin_amdgcn_mfma_f32_16x16x32_bf16(a2, bq[2][2], acc, 0, 0, 0);
      m2 = fminf(fminf(fminf(acc[0], acc[1]), acc[2]), fminf(acc[3], m2));

      acc = __builtin_amdgcn_mfma_f32_16x16x32_bf16(a0, bq[3][0], y2v, 0, 0, 0);
      acc = __builtin_amdgcn_mfma_f32_16x16x32_bf16(a1, bq[3][1], acc, 0, 0, 0);
      acc = __builtin_amdgcn_mfma_f32_16x16x32_bf16(a2, bq[3][2], acc, 0, 0, 0);
      m3 = fminf(fminf(fminf(acc[0], acc[1]), acc[2]), fminf(acc[3], m3));
    }
  }

  // fold across quads (lanes with equal n hold the same query columns)
  float m[4] = {m0, m1, m2, m3};
  #pragma unroll
  for (int ct = 0; ct < 4; ++ct) {
    m[ct] = fminf(m[ct], __shfl_xor(m[ct], 16, 64));
    m[ct] = fminf(m[ct], __shfl_xor(m[ct], 32, 64));
  }
  if (quad == 0) {
    #pragma unroll
    for (int ct = 0; ct < 4; ++ct) {
      int q = qbase + ct * 16 + n;
      float sq = fmaxf(x2[q] + m[ct], 0.0f);
      float val = sqrtf(sq) * 10.0f;
      atomicMin((unsigned int*)&outp[q], __float_as_uint(val));
    }
  }
}

extern "C" void kernel_launch(void* const* d_in, const int* in_sizes, int n_in,
                              void* d_out, int out_size, void* d_ws, size_t ws_size,
                              hipStream_t stream) {
  const float* qf = (const float*)d_in[0];   // mutation_dist 8192x96
  const float* tf = (const float*)d_in[1];   // train_data   65536x96
  float* outp = (float*)d_out;               // 8192 f32

  ushort* qbf = (ushort*)d_ws;                // 8192*96 bf16
  ushort* tbf = qbf + (size_t)NQ * KD;        // 65536*96 bf16, pre-scaled -2
  float* x2 = (float*)(tbf + (size_t)NT * KD);
  float* y2 = x2 + NQ;

  prep_kernel<<<(NQ + NT) / 64, 256, 0, stream>>>(qf, tf, qbf, tbf, x2, y2, outp);
  min_dist_kernel<<<(NQ / QB) * TSPLIT, 256, 0, stream>>>(qbf, tbf, x2, y2, outp);
}